// Round 3
// baseline (73.632 us; speedup 1.0000x reference)
//
#include <hip/hip_runtime.h>

// out[j,i] = sum_k exp(-(x_k - i/512)^2 * 5000) * exp(-(y_k - j/512)^2 * 5000)
// 1024 points (8 curves x 128 steps), 512x512 fp32 output.
//
// K1: grid (4,4,16); each block computes a 128x128 output tile over a 64-wide
//     K-slice with 8x8 fp32 micro-tiles per thread (deep ILP: 64 indep FMAs
//     per 4 ds_read_b128). Partials -> d_ws (16 x 1 MB), plain float4 stores.
// K2: reduce 16 partials -> d_out (fully overwrites; partials are L2-resident).

constexpr int RES_   = 512;
constexpr int TILE   = 128;            // output tile edge
constexpr int KSPLIT = 16;
constexpr int KB     = 1024 / KSPLIT;  // 64 K per block (single LDS chunk)

__global__ __launch_bounds__(256)
void bezier_partial(const float* __restrict__ curves, float* __restrict__ part) {
    __shared__ float xs[KB], ys[KB];
    __shared__ float ex_s[KB][TILE];   // 32 KB
    __shared__ float ey_s[KB][TILE];   // 32 KB

    const int tid   = threadIdx.x;
    const int ibase = blockIdx.x * TILE;   // output columns i
    const int jbase = blockIdx.y * TILE;   // output rows j
    const int kbase = blockIdx.z * KB;     // K slice

    // --- evaluate Bezier sample points (de Casteljau, fp32), threads 0..63 ---
    if (tid < KB) {
        int p = kbase + tid;                       // global point index
        int c = p >> 7;                            // curve 0..7
        float t = (float)(p & 127) * (1.0f / 127.0f);
        const float* cp = curves + c * 8;          // 4 control points x (x,y)
        float p0x = cp[0], p0y = cp[1];
        float p1x = cp[2], p1y = cp[3];
        float p2x = cp[4], p2y = cp[5];
        float p3x = cp[6], p3y = cp[7];
        float a01x = p0x + (p1x - p0x) * t, a01y = p0y + (p1y - p0y) * t;
        float a12x = p1x + (p2x - p1x) * t, a12y = p1y + (p2y - p1y) * t;
        float a23x = p2x + (p3x - p2x) * t, a23y = p2y + (p3y - p2y) * t;
        float qax = a01x + (a12x - a01x) * t, qay = a01y + (a12y - a01y) * t;
        float qbx = a12x + (a23x - a12x) * t, qby = a12y + (a23y - a12y) * t;
        xs[tid] = qax + (qbx - qax) * t;
        ys[tid] = qay + (qby - qay) * t;
    }
    __syncthreads();

    // --- stage exp factor tiles: KB x TILE each, 256 threads, 32 iters/array ---
#pragma unroll
    for (int e = 0; e < (KB * TILE) / 256; ++e) {
        int idx = e * 256 + tid;
        int kk  = idx >> 7;            // TILE == 128
        int ii  = idx & 127;
        float xv = xs[kk];             // wave-uniform -> LDS broadcast
        float yv = ys[kk];
        float dx = xv - (float)(ibase + ii) * (1.0f / 512.0f);
        float dy = yv - (float)(jbase + ii) * (1.0f / 512.0f);
        ex_s[kk][ii] = __expf(dx * dx * (-5000.0f));
        ey_s[kk][ii] = __expf(dy * dy * (-5000.0f));
    }
    __syncthreads();

    const int it = tid & 15, jt = tid >> 4;
    const int ib = it * 8, jb = jt * 8;    // 8x8 micro-tile origin in tile
    float acc[8][8];
#pragma unroll
    for (int r = 0; r < 8; ++r)
#pragma unroll
        for (int c = 0; c < 8; ++c) acc[r][c] = 0.0f;

    // --- 8x8 outer-product accumulation over KB ---
#pragma unroll 2
    for (int kk = 0; kk < KB; ++kk) {
        const float4 a0 = *reinterpret_cast<const float4*>(&ex_s[kk][ib]);
        const float4 a1 = *reinterpret_cast<const float4*>(&ex_s[kk][ib + 4]);
        const float4 b0 = *reinterpret_cast<const float4*>(&ey_s[kk][jb]);
        const float4 b1 = *reinterpret_cast<const float4*>(&ey_s[kk][jb + 4]);
        const float av[8] = {a0.x, a0.y, a0.z, a0.w, a1.x, a1.y, a1.z, a1.w};
        const float bv[8] = {b0.x, b0.y, b0.z, b0.w, b1.x, b1.y, b1.z, b1.w};
#pragma unroll
        for (int r = 0; r < 8; ++r)
#pragma unroll
            for (int c = 0; c < 8; ++c)
                acc[r][c] += bv[r] * av[c];
    }

    // --- store partial tile: plain coalesced float4 stores, no atomics ---
    float* slice = part + (size_t)blockIdx.z * (RES_ * RES_);
#pragma unroll
    for (int r = 0; r < 8; ++r) {
        int j = jbase + jb + r;
        float* row = &slice[j * RES_ + ibase + ib];
        *reinterpret_cast<float4*>(row)     = make_float4(acc[r][0], acc[r][1], acc[r][2], acc[r][3]);
        *reinterpret_cast<float4*>(row + 4) = make_float4(acc[r][4], acc[r][5], acc[r][6], acc[r][7]);
    }
}

__global__ __launch_bounds__(256)
void reduce_k(const float* __restrict__ part, float* __restrict__ out) {
    int i = blockIdx.x * blockDim.x + threadIdx.x;   // float4 index, 65536 total
    const float4* p4 = reinterpret_cast<const float4*>(part);
    float4 s = p4[i];
#pragma unroll
    for (int z = 1; z < KSPLIT; ++z) {
        float4 v = p4[(size_t)z * (RES_ * RES_ / 4) + i];
        s.x += v.x; s.y += v.y; s.z += v.z; s.w += v.w;
    }
    reinterpret_cast<float4*>(out)[i] = s;
}

extern "C" void kernel_launch(void* const* d_in, const int* in_sizes, int n_in,
                              void* d_out, int out_size, void* d_ws, size_t ws_size,
                              hipStream_t stream) {
    const float* curves = (const float*)d_in[0];
    float* out  = (float*)d_out;
    float* part = (float*)d_ws;   // 16 MB of partials

    dim3 grid(RES_ / TILE, RES_ / TILE, KSPLIT);     // (4, 4, 16) = 256 blocks
    bezier_partial<<<grid, dim3(256), 0, stream>>>(curves, part);

    reduce_k<<<dim3(RES_ * RES_ / 4 / 256), dim3(256), 0, stream>>>(part, out);
}